// Round 7
// baseline (56.799 us; speedup 1.0000x reference)
//
#include <hip/hip_runtime.h>
#include <stdint.h>

#define OUTD 4000
#define NPAD 4096
#define CC 16
#define WW 48
#define HH 48
#define BB 128
#define KD 768          // C*H contraction depth
#define MD 6144         // B*W rows
#define EPSF 1e-6f

#define BM 192          // 4 batches * 48 w
#define BN 128
#define BKU 32          // K elems per pipeline unit
#define UNITS 24        // 768/32
#define SLOT_ELEMS ((BM + BN) * BKU)   // 10240 elems = 20 KB
#define THREADS 256
#define XPB 2304        // blocks for x-conversion in prep_all

using short8 = __attribute__((ext_vector_type(8))) short;
using f32x4  = __attribute__((ext_vector_type(4))) float;

static __device__ __forceinline__ unsigned short f2bf(float f) {
  union { float f; unsigned int u; } v; v.f = f;
  unsigned int u = v.u;
  unsigned int r = (u + 0x7FFFu + ((u >> 16) & 1u)) >> 16;
  return (unsigned short)r;
}

// ---------------- Fused prep: blocks [0,XPB) convert x -> A (bf16, merged (c,h) K axis);
// blocks [XPB, XPB+1024) normalize weights -> Qt (bf16) + wnT (f32, [48][4096]).
__global__ __launch_bounds__(256)
void prep_all(const float* __restrict__ x,
              const float* __restrict__ width,
              const float* __restrict__ height,
              const float* __restrict__ feat,
              unsigned short* __restrict__ A,
              unsigned short* __restrict__ Qt,
              float* __restrict__ wnT) {
  __shared__ float smw[4][WW];
  int bid = blockIdx.x;
  if (bid < XPB) {
    int t = bid * 256 + threadIdx.x;      // XPB*256 == BB*CC*WW*HH/8 exactly
    int e = t * 8;
    int h0 = e % HH;                      // 8 | 48: the 8 elems share (b,c,w)
    int w = (e / HH) % WW;
    int c = (e / (HH * WW)) % CC;
    int b = e / (HH * WW * CC);
    float4 v0 = *(const float4*)(x + e);
    float4 v1 = *(const float4*)(x + e + 4);
    short8 o;
    o[0] = (short)f2bf(v0.x); o[1] = (short)f2bf(v0.y);
    o[2] = (short)f2bf(v0.z); o[3] = (short)f2bf(v0.w);
    o[4] = (short)f2bf(v1.x); o[5] = (short)f2bf(v1.y);
    o[6] = (short)f2bf(v1.z); o[7] = (short)f2bf(v1.w);
    *(short8*)&A[(size_t)(b * WW + w) * KD + c * HH + h0] = o;
  } else {
    int lane = threadIdx.x & 63;
    int wv = threadIdx.x >> 6;            // wave 0..3
    int nbase = (bid - XPB) * 4;
    int n = nbase + wv;                   // 0..4095
    bool valid = (n < OUTD);
    float hv = (valid && lane < HH) ? height[n * HH + lane] : 0.f;
    float wvv = (valid && lane < WW) ? width[n * WW + lane] : 0.f;
    float hs = hv * hv, wsum = wvv * wvv;
    #pragma unroll
    for (int off = 32; off > 0; off >>= 1) {
      hs += __shfl_xor(hs, off);
      wsum += __shfl_xor(wsum, off);
    }
    float hnorm = rsqrtf(hs + EPSF);
    float wnorm = rsqrtf(wsum + EPSF);
    if (lane < WW) smw[wv][lane] = wvv * wnorm;   // 0 for invalid n
    if (valid) {
      #pragma unroll
      for (int i = lane; i < KD; i += 64) {
        int c = i / HH, h = i % HH;
        Qt[(size_t)n * KD + i] = f2bf(feat[n * CC + c] * height[n * HH + h] * hnorm);
      }
    } else {
      #pragma unroll
      for (int i = lane; i < KD; i += 64) Qt[(size_t)n * KD + i] = 0;
    }
    __syncthreads();
    if (threadIdx.x < WW) {
      int w = threadIdx.x;
      float4 o = make_float4(smw[0][w], smw[1][w], smw[2][w], smw[3][w]);
      *(float4*)&wnT[w * NPAD + nbase] = o;
    }
  }
}

// ---------------- Main GEMM: P = A (6144x768) * Qt^T (768x4096), fused w-reduction epilogue.
// 192x128 tile, 4 waves (2m x 2n), wave tile 96x64. Ring of THREE 20 KB LDS slots (60 KB)
// -> 2 resident blocks/CU (120 KB < 160 KB) for cross-block latency hiding. Staging depth 2,
// counted vmcnt(5); ds_reads pipelined one unit ahead into double-buffered registers.
__global__ __launch_bounds__(THREADS, 2)
void gemm_main(const unsigned short* __restrict__ A,   // [6144][768] bf16 bits
               const unsigned short* __restrict__ Qt,  // [4096][768] bf16 bits
               const float* __restrict__ wnT,          // [48][4096]
               const float* __restrict__ bias,         // [4000]
               float* __restrict__ out) {              // [128][4000]
  __shared__ unsigned short S[3 * SLOT_ELEMS];   // 61440 B -> 2 blocks/CU

  int tid = threadIdx.x;
  int lane = tid & 63;
  int wid = tid >> 6;          // 0..3
  int wm = wid >> 1;           // 0..1 -> 96-row slice of the tile
  int wnh = wid & 1;           // 0..1 -> 64-col half

  // XCD-local mapping: XCD k (= bid&7) owns by in [4k, 4k+4), sweeps bx.
  int bid = blockIdx.x;        // 0..1023
  int xcd = bid & 7;
  int i = bid >> 3;            // 0..127
  int by = xcd * 4 + (i & 3);  // m tile 0..31
  int bx = i >> 2;             // n tile 0..31
  int n0 = bx * BN;
  int m0 = by * BM;

  // ---- staging: per wave 3 A-loads + 2 B-loads per unit (each: 16 rows x 32 elems = 1KB).
  // LDS dest linear; global source granule XOR-pre-swizzled: LDS[row][g*8..] holds
  // global[row][(g ^ ((row>>1)&3))*8..]  (granule = 8 elems = 16B, row = 64B).
  int lrow = lane >> 2;              // 0..15 row within chunk
  int g = lane & 3;                  // granule within 32-elem row
  int gsw = (g ^ ((lrow >> 1) & 3)) * 8;
  const unsigned short* gA0 = A + (size_t)(m0 + (wid * 3 + 0) * 16 + lrow) * KD + gsw;
  const unsigned short* gA1 = A + (size_t)(m0 + (wid * 3 + 1) * 16 + lrow) * KD + gsw;
  const unsigned short* gA2 = A + (size_t)(m0 + (wid * 3 + 2) * 16 + lrow) * KD + gsw;
  const unsigned short* gB0 = Qt + (size_t)(n0 + (wid * 2 + 0) * 16 + lrow) * KD + gsw;
  const unsigned short* gB1 = Qt + (size_t)(n0 + (wid * 2 + 1) * 16 + lrow) * KD + gsw;
  int aD0 = (wid * 3 + 0) * 512;     // elem offsets of chunk bases within a slot
  int aD1 = (wid * 3 + 1) * 512;
  int aD2 = (wid * 3 + 2) * 512;
  int bD0 = BM * BKU + (wid * 2 + 0) * 512;
  int bD1 = BM * BKU + (wid * 2 + 1) * 512;

#define SLOTB(u) (((u) % 3) * SLOT_ELEMS)
#define STAGE(u)                                                                  \
  { __builtin_amdgcn_global_load_lds(                                             \
        (const __attribute__((address_space(1))) void*)(gA0 + (u) * BKU),         \
        (__attribute__((address_space(3))) void*)(&S[SLOTB(u) + aD0]), 16, 0, 0); \
    __builtin_amdgcn_global_load_lds(                                             \
        (const __attribute__((address_space(1))) void*)(gA1 + (u) * BKU),         \
        (__attribute__((address_space(3))) void*)(&S[SLOTB(u) + aD1]), 16, 0, 0); \
    __builtin_amdgcn_global_load_lds(                                             \
        (const __attribute__((address_space(1))) void*)(gA2 + (u) * BKU),         \
        (__attribute__((address_space(3))) void*)(&S[SLOTB(u) + aD2]), 16, 0, 0); \
    __builtin_amdgcn_global_load_lds(                                             \
        (const __attribute__((address_space(1))) void*)(gB0 + (u) * BKU),         \
        (__attribute__((address_space(3))) void*)(&S[SLOTB(u) + bD0]), 16, 0, 0); \
    __builtin_amdgcn_global_load_lds(                                             \
        (const __attribute__((address_space(1))) void*)(gB1 + (u) * BKU),         \
        (__attribute__((address_space(3))) void*)(&S[SLOTB(u) + bD1]), 16, 0, 0); }

  // ---- ds_read offsets (elem) with matching swizzle; rows are 32 elems (64B).
  int q16 = lane & 15;
  int hi = lane >> 4;                // 0..3 -> k-granule
  int kq = (q16 >> 1) & 3;
  int aoff = (wm * 96 + q16) * BKU + (hi ^ kq) * 8;             // + mi*512
  int boff = BM * BKU + (wnh * 64 + q16) * BKU + (hi ^ kq) * 8; // + ni*512

  f32x4 acc[6][4] = {};
  short8 afr[2][6];
  short8 bfr[2][4];

#define DSREAD(set, u)                                          \
  { const unsigned short* sb = &S[SLOTB(u)];                    \
    afr[set][0] = *(const short8*)&sb[aoff];                    \
    afr[set][1] = *(const short8*)&sb[aoff + 512];              \
    afr[set][2] = *(const short8*)&sb[aoff + 1024];             \
    afr[set][3] = *(const short8*)&sb[aoff + 1536];             \
    afr[set][4] = *(const short8*)&sb[aoff + 2048];             \
    afr[set][5] = *(const short8*)&sb[aoff + 2560];             \
    bfr[set][0] = *(const short8*)&sb[boff];                    \
    bfr[set][1] = *(const short8*)&sb[boff + 512];              \
    bfr[set][2] = *(const short8*)&sb[boff + 1024];             \
    bfr[set][3] = *(const short8*)&sb[boff + 1536]; }

  // Prologue: 2 units in flight (10 loads/wave); read unit 0 into reg set 0.
  STAGE(0); STAGE(1);
  asm volatile("s_waitcnt vmcnt(5)" ::: "memory");
  __builtin_amdgcn_s_barrier();
  __builtin_amdgcn_sched_barrier(0);
  DSREAD(0, 0);
  __builtin_amdgcn_sched_barrier(0);

  #pragma unroll
  for (int u = 0; u < UNITS; ++u) {
    if (u + 2 < UNITS) STAGE(u + 2);           // refill slot (u-1)%3
    if (u + 1 < UNITS) {
      // own-wave wait: unit u+1's 5 loads landed
      if (u <= UNITS - 3) asm volatile("s_waitcnt vmcnt(5)" ::: "memory");
      else                asm volatile("s_waitcnt vmcnt(0)" ::: "memory");
      __builtin_amdgcn_s_barrier();            // all waves' u+1 loads landed;
                                               // also: all waves done reading slot u-1
      __builtin_amdgcn_sched_barrier(0);
      DSREAD((u + 1) & 1, u + 1);              // overlaps with MFMA(u) below
      __builtin_amdgcn_sched_barrier(0);
    }
    const int cs = u & 1;
    __builtin_amdgcn_s_setprio(1);
    #pragma unroll
    for (int ni = 0; ni < 4; ++ni)
      #pragma unroll
      for (int mi = 0; mi < 6; ++mi)
        acc[mi][ni] = __builtin_amdgcn_mfma_f32_16x16x32_bf16(afr[cs][mi], bfr[cs][ni], acc[mi][ni], 0, 0, 0);
    __builtin_amdgcn_s_setprio(0);
    __builtin_amdgcn_sched_barrier(0);
  }

  // ---- Epilogue: y[b,n] = sum_w wnT[w][n] * P[(b,w),n] + bias[n]
  // wave rows: wm*96 + mi*16 + hi*4 + rr; batch = by*4 + wm*2 + (mi>=3); w = (mi%3)*16+hi*4+rr.
  int b0 = by * 4 + wm * 2;
  #pragma unroll
  for (int ni = 0; ni < 4; ++ni) {
    int ng = n0 + wnh * 64 + ni * 16 + q16;
    float s0 = 0.f, s1 = 0.f;
    #pragma unroll
    for (int mi = 0; mi < 3; ++mi) {
      int wbase = mi * 16 + hi * 4;
      f32x4 va = acc[mi][ni];
      f32x4 vb = acc[mi + 3][ni];
      #pragma unroll
      for (int r = 0; r < 4; ++r) {
        float t = wnT[(wbase + r) * NPAD + ng];
        s0 += t * va[r];
        s1 += t * vb[r];
      }
    }
    s0 += __shfl_xor(s0, 16); s0 += __shfl_xor(s0, 32);
    s1 += __shfl_xor(s1, 16); s1 += __shfl_xor(s1, 32);
    if (hi == 0 && ng < OUTD) {
      float bv = bias[ng];
      out[(size_t)b0 * OUTD + ng] = s0 + bv;
      out[(size_t)(b0 + 1) * OUTD + ng] = s1 + bv;
    }
  }
#undef STAGE
#undef SLOTB
#undef DSREAD
}

extern "C" void kernel_launch(void* const* d_in, const int* in_sizes, int n_in,
                              void* d_out, int out_size, void* d_ws, size_t ws_size,
                              hipStream_t stream) {
  const float* x      = (const float*)d_in[0];
  const float* width  = (const float*)d_in[1];
  const float* height = (const float*)d_in[2];
  const float* feat   = (const float*)d_in[3];
  const float* bias   = (const float*)d_in[4];
  float* out = (float*)d_out;

  char* ws = (char*)d_ws;
  unsigned short* A  = (unsigned short*)ws;                        // 6144*768*2 = 9,437,184
  unsigned short* Qt = (unsigned short*)(ws + 9437184);            // 4096*768*2 = 6,291,456
  float* wnT         = (float*)(ws + 9437184 + 6291456);           // 48*4096*4  =   786,432

  prep_all<<<dim3(XPB + NPAD / 4), dim3(256), 0, stream>>>(x, width, height, feat, A, Qt, wnT);
  gemm_main<<<dim3(1024), dim3(THREADS), 0, stream>>>(A, Qt, wnT, bias, out);
}

// Round 8
// 49.876 us; speedup vs baseline: 1.1388x; 1.1388x over previous
//
#include <hip/hip_runtime.h>
#include <stdint.h>

#define OUTD 4000
#define NPAD 4096
#define CC 16
#define WW 48
#define HH 48
#define BB 128
#define KD 768          // C*H contraction depth
#define MD 6144         // B*W rows
#define EPSF 1e-6f

#define BM 384          // 8 batches * 48 w
#define BN 128
#define BKU 64          // K elems per pipeline unit (one barrier per unit)
#define UNITS 12        // 768/64
#define AELEMS (BM * BKU)              // 24576 elems
#define SLOT_ELEMS ((BM + BN) * BKU)   // 32768 elems = 64 KB
#define THREADS 512
#define XPB 2304        // blocks for x-conversion in prep_all

using short8 = __attribute__((ext_vector_type(8))) short;
using f32x4  = __attribute__((ext_vector_type(4))) float;

static __device__ __forceinline__ unsigned short f2bf(float f) {
  union { float f; unsigned int u; } v; v.f = f;
  unsigned int u = v.u;
  unsigned int r = (u + 0x7FFFu + ((u >> 16) & 1u)) >> 16;
  return (unsigned short)r;
}

// ---------------- Fused prep: blocks [0,XPB) convert x -> A (bf16, merged (c,h) K axis);
// blocks [XPB, XPB+1024) normalize weights -> Qt (bf16) + wnT (f32, [48][4096]).
__global__ __launch_bounds__(256)
void prep_all(const float* __restrict__ x,
              const float* __restrict__ width,
              const float* __restrict__ height,
              const float* __restrict__ feat,
              unsigned short* __restrict__ A,
              unsigned short* __restrict__ Qt,
              float* __restrict__ wnT) {
  __shared__ float smw[4][WW];
  int bid = blockIdx.x;
  if (bid < XPB) {
    int t = bid * 256 + threadIdx.x;      // XPB*256 == BB*CC*WW*HH/8 exactly
    int e = t * 8;
    int h0 = e % HH;                      // 8 | 48: the 8 elems share (b,c,w)
    int w = (e / HH) % WW;
    int c = (e / (HH * WW)) % CC;
    int b = e / (HH * WW * CC);
    float4 v0 = *(const float4*)(x + e);
    float4 v1 = *(const float4*)(x + e + 4);
    short8 o;
    o[0] = (short)f2bf(v0.x); o[1] = (short)f2bf(v0.y);
    o[2] = (short)f2bf(v0.z); o[3] = (short)f2bf(v0.w);
    o[4] = (short)f2bf(v1.x); o[5] = (short)f2bf(v1.y);
    o[6] = (short)f2bf(v1.z); o[7] = (short)f2bf(v1.w);
    *(short8*)&A[(size_t)(b * WW + w) * KD + c * HH + h0] = o;
  } else {
    int lane = threadIdx.x & 63;
    int wv = threadIdx.x >> 6;            // wave 0..3
    int nbase = (bid - XPB) * 4;
    int n = nbase + wv;                   // 0..4095
    bool valid = (n < OUTD);
    float hv = (valid && lane < HH) ? height[n * HH + lane] : 0.f;
    float wvv = (valid && lane < WW) ? width[n * WW + lane] : 0.f;
    float hs = hv * hv, wsum = wvv * wvv;
    #pragma unroll
    for (int off = 32; off > 0; off >>= 1) {
      hs += __shfl_xor(hs, off);
      wsum += __shfl_xor(wsum, off);
    }
    float hnorm = rsqrtf(hs + EPSF);
    float wnorm = rsqrtf(wsum + EPSF);
    if (lane < WW) smw[wv][lane] = wvv * wnorm;   // 0 for invalid n
    if (valid) {
      #pragma unroll
      for (int i = lane; i < KD; i += 64) {
        int c = i / HH, h = i % HH;
        Qt[(size_t)n * KD + i] = f2bf(feat[n * CC + c] * height[n * HH + h] * hnorm);
      }
    } else {
      #pragma unroll
      for (int i = lane; i < KD; i += 64) Qt[(size_t)n * KD + i] = 0;
    }
    __syncthreads();
    if (threadIdx.x < WW) {
      int w = threadIdx.x;
      float4 o = make_float4(smw[0][w], smw[1][w], smw[2][w], smw[3][w]);
      *(float4*)&wnT[w * NPAD + nbase] = o;
    }
  }
}

// ---------------- Main GEMM: P = A (6144x768) * Qt^T (768x4096), fused w-reduction epilogue.
// 384x128 tile, 8 waves (4m x 2n), wave tile 96x64. Units of BK=64, ring of 2 LDS slots
// (128 KB), ONE barrier per unit, counted vmcnt(8). Per unit: k-half-1 ds_reads issued
// before the k-half-0 MFMA cluster so they complete under it.
__global__ __launch_bounds__(THREADS, 2)
void gemm_main(const unsigned short* __restrict__ A,   // [6144][768] bf16 bits
               const unsigned short* __restrict__ Qt,  // [4096][768] bf16 bits
               const float* __restrict__ wnT,          // [48][4096]
               const float* __restrict__ bias,         // [4000]
               float* __restrict__ out) {              // [128][4000]
  __shared__ unsigned short S[2 * SLOT_ELEMS];   // 131072 B -> 1 block/CU

  int tid = threadIdx.x;
  int lane = tid & 63;
  int wid = tid >> 6;          // 0..7
  int wm = wid >> 1;           // 0..3 -> 96-row slice of the tile
  int wnh = wid & 1;           // 0..1 -> 64-col half

  // XCD-local mapping: XCD k (= bid&7) owns by in {2k, 2k+1}, sweeps bx.
  int bid = blockIdx.x;        // 0..511
  int xcd = bid & 7;
  int i = bid >> 3;            // 0..63
  int by = xcd * 2 + (i & 1);  // m tile 0..15
  int bx = i >> 1;             // n tile 0..31
  int n0 = bx * BN;
  int m0 = by * BM;

  // ---- staging: per wave 6 A-loads + 2 B-loads per unit (each: 8 rows x 64 elems = 1KB).
  // LDS dest linear; global source granule XOR-pre-swizzled: LDS[row][g*8..] holds
  // global[row][(g ^ (row&7))*8..]  (granule = 8 elems = 16B, row = 128B).
  int rsub = lane >> 3;              // 0..7 row within 8-row chunk
  int cg = lane & 7;                 // granule within 64-elem row
  int gsw = (cg ^ rsub) * 8;
  const unsigned short* gA[6];
  const unsigned short* gB[2];
  #pragma unroll
  for (int j = 0; j < 6; ++j)
    gA[j] = A + (size_t)(m0 + (wid * 6 + j) * 8 + rsub) * KD + gsw;
  #pragma unroll
  for (int j = 0; j < 2; ++j)
    gB[j] = Qt + (size_t)(n0 + (wid * 2 + j) * 8 + rsub) * KD + gsw;
  int aD[6], bD[2];
  #pragma unroll
  for (int j = 0; j < 6; ++j) aD[j] = (wid * 6 + j) * 512;
  #pragma unroll
  for (int j = 0; j < 2; ++j) bD[j] = AELEMS + (wid * 2 + j) * 512;

#define SLOTB(u) (((u) & 1) * SLOT_ELEMS)
#define STAGE(u)                                                                    \
  { _Pragma("unroll")                                                               \
    for (int j = 0; j < 6; ++j)                                                     \
      __builtin_amdgcn_global_load_lds(                                             \
          (const __attribute__((address_space(1))) void*)(gA[j] + (u) * BKU),       \
          (__attribute__((address_space(3))) void*)(&S[SLOTB(u) + aD[j]]), 16, 0, 0); \
    _Pragma("unroll")                                                               \
    for (int j = 0; j < 2; ++j)                                                     \
      __builtin_amdgcn_global_load_lds(                                             \
          (const __attribute__((address_space(1))) void*)(gB[j] + (u) * BKU),       \
          (__attribute__((address_space(3))) void*)(&S[SLOTB(u) + bD[j]]), 16, 0, 0); }

  // ---- ds_read offsets (elem) with matching swizzle; rows are 64 elems (128B).
  // frag read: row = (q16 within 16-row frag), granule = kh*4 + hi, swizzled by row&7.
  int q16 = lane & 15;
  int hi = lane >> 4;                // 0..3 -> k-granule within half
  int q7 = q16 & 7;
  int aofs[2], bofs[2];              // [khalf] base offsets (add mi*16*64 / ni*16*64)
  #pragma unroll
  for (int kh = 0; kh < 2; ++kh) {
    aofs[kh] = (wm * 96 + q16) * BKU + (((kh * 4 + hi) ^ q7) * 8);
    bofs[kh] = AELEMS + (wnh * 64 + q16) * BKU + (((kh * 4 + hi) ^ q7) * 8);
  }

  f32x4 acc[6][4] = {};
  short8 afA[6], bfA[4], afB[6], bfB[4];

#define DSREAD_H(afX, bfX, u, kh)                                      \
  { const unsigned short* sb = &S[SLOTB(u)];                           \
    _Pragma("unroll")                                                  \
    for (int mi = 0; mi < 6; ++mi)                                     \
      afX[mi] = *(const short8*)&sb[aofs[kh] + mi * 16 * BKU];         \
    _Pragma("unroll")                                                  \
    for (int ni = 0; ni < 4; ++ni)                                     \
      bfX[ni] = *(const short8*)&sb[bofs[kh] + ni * 16 * BKU]; }

#define MFMA24(afX, bfX)                                               \
  { _Pragma("unroll")                                                  \
    for (int ni = 0; ni < 4; ++ni)                                     \
      _Pragma("unroll")                                                \
      for (int mi = 0; mi < 6; ++mi)                                   \
        acc[mi][ni] = __builtin_amdgcn_mfma_f32_16x16x32_bf16(afX[mi], bfX[ni], acc[mi][ni], 0, 0, 0); }

  // Prologue: stage unit 0.
  STAGE(0);

  #pragma unroll
  for (int u = 0; u < UNITS; ++u) {
    if (u + 1 < UNITS) STAGE(u + 1);           // 8 loads -> other slot
    if (u + 1 < UNITS) asm volatile("s_waitcnt vmcnt(8)" ::: "memory");  // unit u landed
    else               asm volatile("s_waitcnt vmcnt(0)" ::: "memory");
    __builtin_amdgcn_s_barrier();              // all waves: slot u ready
    __builtin_amdgcn_sched_barrier(0);

    DSREAD_H(afA, bfA, u, 0);                  // k-half 0 reads (exposed burst)
    asm volatile("s_waitcnt lgkmcnt(0)" ::: "memory");
    __builtin_amdgcn_sched_barrier(0);
    DSREAD_H(afB, bfB, u, 1);                  // k-half 1 reads: complete under MFMA0
    __builtin_amdgcn_s_setprio(1);
    MFMA24(afA, bfA);
    asm volatile("s_waitcnt lgkmcnt(0)" ::: "memory");
    __builtin_amdgcn_sched_barrier(0);
    MFMA24(afB, bfB);
    __builtin_amdgcn_s_setprio(0);
    __builtin_amdgcn_sched_barrier(0);
    // no trailing barrier: each wave's slot-u reads are lgkm-drained before its
    // MFMA cluster ends, which precedes barrier(u+1), which precedes STAGE(u+2).
  }

  // ---- Epilogue: y[b,n] = sum_w wnT[w][n] * P[(b,w),n] + bias[n]
  // wave rows: wm*96 + mi*16 + hi*4 + rr; batch = by*8 + wm*2 + (mi>=3); w = (mi%3)*16+hi*4+rr.
  int b0 = by * 8 + wm * 2;
  #pragma unroll
  for (int ni = 0; ni < 4; ++ni) {
    int ng = n0 + wnh * 64 + ni * 16 + q16;
    float s0 = 0.f, s1 = 0.f;
    #pragma unroll
    for (int mi = 0; mi < 3; ++mi) {
      int wbase = mi * 16 + hi * 4;
      f32x4 va = acc[mi][ni];
      f32x4 vb = acc[mi + 3][ni];
      #pragma unroll
      for (int r = 0; r < 4; ++r) {
        float t = wnT[(wbase + r) * NPAD + ng];
        s0 += t * va[r];
        s1 += t * vb[r];
      }
    }
    s0 += __shfl_xor(s0, 16); s0 += __shfl_xor(s0, 32);
    s1 += __shfl_xor(s1, 16); s1 += __shfl_xor(s1, 32);
    if (hi == 0 && ng < OUTD) {
      float bv = bias[ng];
      out[(size_t)b0 * OUTD + ng] = s0 + bv;
      out[(size_t)(b0 + 1) * OUTD + ng] = s1 + bv;
    }
  }
#undef STAGE
#undef SLOTB
#undef DSREAD_H
#undef MFMA24
}

extern "C" void kernel_launch(void* const* d_in, const int* in_sizes, int n_in,
                              void* d_out, int out_size, void* d_ws, size_t ws_size,
                              hipStream_t stream) {
  const float* x      = (const float*)d_in[0];
  const float* width  = (const float*)d_in[1];
  const float* height = (const float*)d_in[2];
  const float* feat   = (const float*)d_in[3];
  const float* bias   = (const float*)d_in[4];
  float* out = (float*)d_out;

  char* ws = (char*)d_ws;
  unsigned short* A  = (unsigned short*)ws;                        // 6144*768*2 = 9,437,184
  unsigned short* Qt = (unsigned short*)(ws + 9437184);            // 4096*768*2 = 6,291,456
  float* wnT         = (float*)(ws + 9437184 + 6291456);           // 48*4096*4  =   786,432

  prep_all<<<dim3(XPB + NPAD / 4), dim3(256), 0, stream>>>(x, width, height, feat, A, Qt, wnT);
  gemm_main<<<dim3(512), dim3(THREADS), 0, stream>>>(A, Qt, wnT, bias, out);
}